// Round 3
// baseline (956.195 us; speedup 1.0000x reference)
//
#include <hip/hip_runtime.h>

// Geodesic shooting (Hamiltonian RK4) on MI355X.
// State layout everywhere: s[0 .. CN*3) = c (control points), s[CN*3 .. 2*CN*3) = m (momentum).
// dyn(s) = [K@m, 2 * sum_j (mi.mj) Kij (ci - cj)]  with K = exp(-||ci-cj||^2), sigma=1.

#define CN   8192
#define TPB  256
#define IGRP 512            // i's per block (2 per thread)
#define NIB  (CN / IGRP)    // 16 i-groups
#define JT   128            // j-tile staged in LDS
#define SSZ  (2 * CN * 3)   // floats per state

// sqrt(log2(e)): pre-scale coords so exp(-d2) == v_exp_f32(-d2_scaled), no mul.
#define CSCALE 1.2011224087864498f
#define FSCALE (2.0f / CSCALE)   // folds the coordinate scale back out of the force

__global__ __launch_bounds__(TPB) void dyn_partial_kernel(
    const float* __restrict__ s, float* __restrict__ part, int jchunk)
{
    const float* __restrict__ cpt = s;
    const float* __restrict__ mpt = s + CN * 3;
    __shared__ float sc[JT * 3];   // pre-scaled c
    __shared__ float sm[JT * 3];
    const int tid = threadIdx.x;
    const int i0  = blockIdx.x * IGRP + tid;
    const int i1  = i0 + TPB;

    const float ci0x = cpt[i0*3+0]*CSCALE, ci0y = cpt[i0*3+1]*CSCALE, ci0z = cpt[i0*3+2]*CSCALE;
    const float mi0x = mpt[i0*3+0], mi0y = mpt[i0*3+1], mi0z = mpt[i0*3+2];
    const float ci1x = cpt[i1*3+0]*CSCALE, ci1y = cpt[i1*3+1]*CSCALE, ci1z = cpt[i1*3+2]*CSCALE;
    const float mi1x = mpt[i1*3+0], mi1y = mpt[i1*3+1], mi1z = mpt[i1*3+2];

    float g0x=0.f,g0y=0.f,g0z=0.f, f0x=0.f,f0y=0.f,f0z=0.f;
    float g1x=0.f,g1y=0.f,g1z=0.f, f1x=0.f,f1y=0.f,f1z=0.f;

    const int jbeg = blockIdx.y * jchunk;
    for (int t0 = 0; t0 < jchunk; t0 += JT) {
        __syncthreads();
        const int base = (jbeg + t0) * 3;
        for (int t = tid; t < JT * 3; t += TPB) {
            sc[t] = cpt[base + t] * CSCALE;
            sm[t] = mpt[base + t];
        }
        __syncthreads();
#pragma unroll 4
        for (int jj = 0; jj < JT; ++jj) {
            const float cjx = sc[jj*3+0], cjy = sc[jj*3+1], cjz = sc[jj*3+2];
            const float mjx = sm[jj*3+0], mjy = sm[jj*3+1], mjz = sm[jj*3+2];
            {
                const float dx = ci0x - cjx, dy = ci0y - cjy, dz = ci0z - cjz;
                const float d2 = dx*dx + dy*dy + dz*dz;          // scaled by log2(e)
                const float e  = __builtin_amdgcn_exp2f(-d2);    // v_exp_f32: 2^(-d2) = exp(-||.||^2)
                const float md = mi0x*mjx + mi0y*mjy + mi0z*mjz;
                const float w  = md * e;
                g0x += e*mjx; g0y += e*mjy; g0z += e*mjz;
                f0x += w*dx;  f0y += w*dy;  f0z += w*dz;
            }
            {
                const float dx = ci1x - cjx, dy = ci1y - cjy, dz = ci1z - cjz;
                const float d2 = dx*dx + dy*dy + dz*dz;
                const float e  = __builtin_amdgcn_exp2f(-d2);
                const float md = mi1x*mjx + mi1y*mjy + mi1z*mjz;
                const float w  = md * e;
                g1x += e*mjx; g1y += e*mjy; g1z += e*mjz;
                f1x += w*dx;  f1y += w*dy;  f1z += w*dz;
            }
        }
    }
    // Partials: part[jb][cd][CN], cd 0..2 = dc (K@m), 3..5 = dm (2*force, rescaled)
    float* p = part + (size_t)blockIdx.y * (6 * CN);
    p[0*CN+i0] = g0x;         p[1*CN+i0] = g0y;         p[2*CN+i0] = g0z;
    p[3*CN+i0] = FSCALE*f0x;  p[4*CN+i0] = FSCALE*f0y;  p[5*CN+i0] = FSCALE*f0z;
    p[0*CN+i1] = g1x;         p[1*CN+i1] = g1y;         p[2*CN+i1] = g1z;
    p[3*CN+i1] = FSCALE*f1x;  p[4*CN+i1] = FSCALE*f1y;  p[5*CN+i1] = FSCALE*f1z;
}

// Reduce partials over S, store k, and (optionally) stmp = sbase + coef*k.
__global__ __launch_bounds__(TPB) void finish_kernel(
    const float* __restrict__ part, int S,
    float* __restrict__ kout,
    const float* __restrict__ sbase,
    float* __restrict__ stmp, float coef)
{
    const int idx = blockIdx.x * TPB + threadIdx.x;   // over 6*CN
    if (idx >= 6 * CN) return;
    const int cd = idx / CN;
    const int i  = idx - cd * CN;
    float acc = 0.f;
    for (int sb = 0; sb < S; ++sb) acc += part[(size_t)sb * (6 * CN) + idx];
    const int comp = cd / 3, d = cd - comp * 3;
    const int off  = comp * CN * 3 + i * 3 + d;       // state layout
    kout[off] = acc;
    if (stmp) stmp[off] = sbase[off] + coef * acc;
}

__global__ __launch_bounds__(TPB) void rk4_final_kernel(
    float* __restrict__ scur,
    const float* __restrict__ k1, const float* __restrict__ k2,
    const float* __restrict__ k3, const float* __restrict__ k4,
    float* __restrict__ outslot, float dt6)
{
    const int idx = blockIdx.x * TPB + threadIdx.x;
    if (idx >= SSZ) return;
    const float v = scur[idx] + dt6 * (k1[idx] + 2.f * (k2[idx] + k3[idx]) + k4[idx]);
    scur[idx]    = v;
    outslot[idx] = v;
}

__global__ __launch_bounds__(TPB) void init_kernel(
    const float* __restrict__ mom, const float* __restrict__ cp,
    float* __restrict__ out, float* __restrict__ scur)
{
    const int idx = blockIdx.x * TPB + threadIdx.x;
    if (idx < 5) out[idx] = 0.25f * (float)idx;      // t_span = linspace(0,1,5)
    if (idx < CN * 3) {
        const float cv = cp[idx], mv = mom[idx];
        scur[idx]            = cv;
        scur[CN * 3 + idx]   = mv;
        out[5 + idx]             = cv;               // st[0][0] = c0
        out[5 + CN * 3 + idx]    = mv;               // st[0][1] = m0
    }
}

extern "C" void kernel_launch(void* const* d_in, const int* in_sizes, int n_in,
                              void* d_out, int out_size, void* d_ws, size_t ws_size,
                              hipStream_t stream)
{
    const float* mom = (const float*)d_in[0];   // momentum [CN][3]
    const float* cp  = (const float*)d_in[1];   // control_points [CN][3]
    float* out = (float*)d_out;
    float* ws  = (float*)d_ws;

    // Workspace layout (floats)
    float* scur = ws;                 // SSZ
    float* stmp = ws + SSZ;           // SSZ
    float* kb0  = ws + 2 * SSZ;       // SSZ
    float* kb1  = ws + 3 * SSZ;
    float* kb2  = ws + 4 * SSZ;
    float* kb3  = ws + 5 * SSZ;
    float* part = ws + 6 * SSZ;       // S * 6 * CN

    // Pick j-split S to fit workspace (deterministic across calls: ws_size fixed).
    size_t avail_f = ws_size / sizeof(float);
    int S = 64;
    while (S > 2 && (size_t)(6 * SSZ) + (size_t)S * 6 * CN > avail_f) S >>= 1;
    const int jchunk = CN / S;

    const float dt = 0.25f;

    init_kernel<<<(CN * 3 + TPB - 1) / TPB, TPB, 0, stream>>>(mom, cp, out, scur);

    dim3 dgrid(NIB, S);
    const int fgrid = (6 * CN + TPB - 1) / TPB;
    const int ugrid = (SSZ + TPB - 1) / TPB;
    float* kb[4] = {kb0, kb1, kb2, kb3};

    for (int step = 0; step < 4; ++step) {
        float* outslot = out + 5 + (size_t)(step + 1) * SSZ;

        dyn_partial_kernel<<<dgrid, TPB, 0, stream>>>(scur, part, jchunk);
        finish_kernel<<<fgrid, TPB, 0, stream>>>(part, S, kb[0], scur, stmp, 0.5f * dt);

        dyn_partial_kernel<<<dgrid, TPB, 0, stream>>>(stmp, part, jchunk);
        finish_kernel<<<fgrid, TPB, 0, stream>>>(part, S, kb[1], scur, stmp, 0.5f * dt);

        dyn_partial_kernel<<<dgrid, TPB, 0, stream>>>(stmp, part, jchunk);
        finish_kernel<<<fgrid, TPB, 0, stream>>>(part, S, kb[2], scur, stmp, dt);

        dyn_partial_kernel<<<dgrid, TPB, 0, stream>>>(stmp, part, jchunk);
        finish_kernel<<<fgrid, TPB, 0, stream>>>(part, S, kb[3], scur, (float*)nullptr, 0.f);

        rk4_final_kernel<<<ugrid, TPB, 0, stream>>>(scur, kb[0], kb[1], kb[2], kb[3],
                                                    outslot, dt / 6.f);
    }
}

// Round 4
// 761.393 us; speedup vs baseline: 1.2558x; 1.2558x over previous
//
#include <hip/hip_runtime.h>

// Geodesic shooting (Hamiltonian RK4) on MI355X.
// dyn(s) = [K@m, 2 * sum_j (mi.mj) Kij (ci - cj)], K = exp(-||ci-cj||^2), sigma=1.

#define CN   8192
#define TPB  128            // dyn block size (2 waves)
#define PTS  2              // i-points per thread
#define IGRP (TPB * PTS)    // 256 i's per block
#define NIB  (CN / IGRP)    // 32 i-groups
#define JT   64             // j-tile staged in LDS
#define SSZ  (2 * CN * 3)   // floats per state

// sqrt(log2(e)): pre-scale coords so exp(-||.||^2) == exp2(-d2_scaled), no mul.
#define CSCALE 1.2011224087864498f
#define FSCALE (2.0f / CSCALE)

__global__ __launch_bounds__(TPB, 8) void dyn_partial_kernel(
    const float* __restrict__ s, float* __restrict__ part, int jchunk)
{
    const float* __restrict__ cpt = s;
    const float* __restrict__ mpt = s + CN * 3;
    __shared__ float4 tile[JT][2];   // [0] = {cx',cy',cz',|c'|^2}, [1] = {mx,my,mz,0}
    const int tid = threadIdx.x;
    const int i0  = blockIdx.x * IGRP + tid;
    const int i1  = i0 + TPB;

    // n = -2*c' so d2 = fma(n, cj', ci2 + cj2) chain; c' reloaded in epilogue.
    float c0x = cpt[i0*3+0]*CSCALE, c0y = cpt[i0*3+1]*CSCALE, c0z = cpt[i0*3+2]*CSCALE;
    float c1x = cpt[i1*3+0]*CSCALE, c1y = cpt[i1*3+1]*CSCALE, c1z = cpt[i1*3+2]*CSCALE;
    const float ci20 = c0x*c0x + c0y*c0y + c0z*c0z;
    const float ci21 = c1x*c1x + c1y*c1y + c1z*c1z;
    const float n0x = -2.f*c0x, n0y = -2.f*c0y, n0z = -2.f*c0z;
    const float n1x = -2.f*c1x, n1y = -2.f*c1y, n1z = -2.f*c1z;
    const float m0x = mpt[i0*3+0], m0y = mpt[i0*3+1], m0z = mpt[i0*3+2];
    const float m1x = mpt[i1*3+0], m1y = mpt[i1*3+1], m1z = mpt[i1*3+2];

    float g0x=0.f,g0y=0.f,g0z=0.f, h0x=0.f,h0y=0.f,h0z=0.f, W0=0.f;
    float g1x=0.f,g1y=0.f,g1z=0.f, h1x=0.f,h1y=0.f,h1z=0.f, W1=0.f;

    const int jbeg = blockIdx.y * jchunk;
    for (int t0 = 0; t0 < jchunk; t0 += JT) {
        __syncthreads();
        {
            const int jj = tid >> 1, half = tid & 1;
            const int gj = jbeg + t0 + jj;
            float4 v;
            if (half == 0) {
                const float cx = cpt[gj*3+0]*CSCALE, cy = cpt[gj*3+1]*CSCALE, cz = cpt[gj*3+2]*CSCALE;
                v = make_float4(cx, cy, cz, cx*cx + cy*cy + cz*cz);
            } else {
                v = make_float4(mpt[gj*3+0], mpt[gj*3+1], mpt[gj*3+2], 0.f);
            }
            tile[jj][half] = v;
        }
        __syncthreads();
#pragma unroll 2
        for (int jj = 0; jj < JT; ++jj) {
            const float4 A = tile[jj][0];   // cj', cj2
            const float4 M = tile[jj][1];   // mj
            {
                const float d2 = fmaf(n0x, A.x, fmaf(n0y, A.y, fmaf(n0z, A.z, ci20 + A.w)));
                const float e  = __builtin_amdgcn_exp2f(-d2);
                const float md = fmaf(m0x, M.x, fmaf(m0y, M.y, m0z * M.z));
                const float w  = md * e;
                g0x = fmaf(e, M.x, g0x); g0y = fmaf(e, M.y, g0y); g0z = fmaf(e, M.z, g0z);
                W0 += w;
                h0x = fmaf(w, A.x, h0x); h0y = fmaf(w, A.y, h0y); h0z = fmaf(w, A.z, h0z);
            }
            {
                const float d2 = fmaf(n1x, A.x, fmaf(n1y, A.y, fmaf(n1z, A.z, ci21 + A.w)));
                const float e  = __builtin_amdgcn_exp2f(-d2);
                const float md = fmaf(m1x, M.x, fmaf(m1y, M.y, m1z * M.z));
                const float w  = md * e;
                g1x = fmaf(e, M.x, g1x); g1y = fmaf(e, M.y, g1y); g1z = fmaf(e, M.z, g1z);
                W1 += w;
                h1x = fmaf(w, A.x, h1x); h1y = fmaf(w, A.y, h1y); h1z = fmaf(w, A.z, h1z);
            }
        }
    }
    // force_true = (ci'*W - h)/CSCALE ; dm = 2*force_true = FSCALE*(ci'*W - h)
    float* p = part + (size_t)blockIdx.y * (6 * CN);
    p[0*CN+i0] = g0x; p[1*CN+i0] = g0y; p[2*CN+i0] = g0z;
    p[3*CN+i0] = FSCALE * fmaf(c0x, W0, -h0x);
    p[4*CN+i0] = FSCALE * fmaf(c0y, W0, -h0y);
    p[5*CN+i0] = FSCALE * fmaf(c0z, W0, -h0z);
    p[0*CN+i1] = g1x; p[1*CN+i1] = g1y; p[2*CN+i1] = g1z;
    p[3*CN+i1] = FSCALE * fmaf(c1x, W1, -h1x);
    p[4*CN+i1] = FSCALE * fmaf(c1y, W1, -h1y);
    p[5*CN+i1] = FSCALE * fmaf(c1z, W1, -h1z);
}

// idx in [0, 6*CN): cd = idx>>13 (plane 0..5), i = idx&8191 -> state offset
__device__ __forceinline__ int state_off(int gidx) {
    const int cd = gidx >> 13, i = gidx & (CN - 1);
    const int comp = (cd >= 3) ? 1 : 0, d = cd - comp * 3;
    return comp * CN * 3 + i * 3 + d;
}

// Reduce partials over S (4 threads/output + LDS combine), store k and stmp.
template<int S>
__global__ __launch_bounds__(256) void finish_kernel(
    const float* __restrict__ part, float* __restrict__ kout,
    const float* __restrict__ sbase, float* __restrict__ stmp, float coef)
{
    constexpr int SQ = S / 4;
    const int tid = threadIdx.x;
    const int sub = tid >> 6, o = tid & 63;
    const int idx = blockIdx.x * 64 + o;
    const float* p = part + (size_t)(sub * SQ) * (6 * CN) + idx;
    float acc = 0.f;
#pragma unroll 8
    for (int r = 0; r < SQ; ++r) acc += p[(size_t)r * (6 * CN)];
    __shared__ float red[256];
    red[tid] = acc;
    __syncthreads();
    if (tid < 64) {
        const float total = red[tid] + red[tid+64] + red[tid+128] + red[tid+192];
        const int off = state_off(blockIdx.x * 64 + tid);
        kout[off] = total;
        stmp[off] = sbase[off] + coef * total;
    }
}

// 4th-stage finish fused with the RK4 combine: scur += dt/6*(k1+2k2+2k3+k4), echo to out.
template<int S>
__global__ __launch_bounds__(256) void finish_final_kernel(
    const float* __restrict__ part,
    const float* __restrict__ k1, const float* __restrict__ k2, const float* __restrict__ k3,
    float* __restrict__ scur, float* __restrict__ outslot, float dt6)
{
    constexpr int SQ = S / 4;
    const int tid = threadIdx.x;
    const int sub = tid >> 6, o = tid & 63;
    const int idx = blockIdx.x * 64 + o;
    const float* p = part + (size_t)(sub * SQ) * (6 * CN) + idx;
    float acc = 0.f;
#pragma unroll 8
    for (int r = 0; r < SQ; ++r) acc += p[(size_t)r * (6 * CN)];
    __shared__ float red[256];
    red[tid] = acc;
    __syncthreads();
    if (tid < 64) {
        const float k4 = red[tid] + red[tid+64] + red[tid+128] + red[tid+192];
        const int off = state_off(blockIdx.x * 64 + tid);
        const float v = scur[off] + dt6 * (k1[off] + 2.f * (k2[off] + k3[off]) + k4);
        scur[off]    = v;
        outslot[off] = v;
    }
}

__global__ __launch_bounds__(256) void init_kernel(
    const float* __restrict__ mom, const float* __restrict__ cp,
    float* __restrict__ out, float* __restrict__ scur)
{
    const int idx = blockIdx.x * 256 + threadIdx.x;
    if (idx < 5) out[idx] = 0.25f * (float)idx;      // t_span
    if (idx < CN * 3) {
        const float cv = cp[idx], mv = mom[idx];
        scur[idx]          = cv;
        scur[CN * 3 + idx] = mv;
        out[5 + idx]            = cv;                // st[0][0] = c0
        out[5 + CN * 3 + idx]   = mv;                // st[0][1] = m0
    }
}

template<int S>
static void run_steps(const float* mom, const float* cp, float* out,
                      float* scur, float* stmp, float* kb0, float* kb1, float* kb2,
                      float* part, hipStream_t stream)
{
    const float dt = 0.25f;
    const int jchunk = CN / S;
    init_kernel<<<(CN * 3 + 255) / 256, 256, 0, stream>>>(mom, cp, out, scur);
    dim3 dgrid(NIB, S);
    const int fgrid = 6 * CN / 64;   // 768
    for (int step = 0; step < 4; ++step) {
        float* outslot = out + 5 + (size_t)(step + 1) * SSZ;
        dyn_partial_kernel<<<dgrid, TPB, 0, stream>>>(scur, part, jchunk);
        finish_kernel<S><<<fgrid, 256, 0, stream>>>(part, kb0, scur, stmp, 0.5f * dt);
        dyn_partial_kernel<<<dgrid, TPB, 0, stream>>>(stmp, part, jchunk);
        finish_kernel<S><<<fgrid, 256, 0, stream>>>(part, kb1, scur, stmp, 0.5f * dt);
        dyn_partial_kernel<<<dgrid, TPB, 0, stream>>>(stmp, part, jchunk);
        finish_kernel<S><<<fgrid, 256, 0, stream>>>(part, kb2, scur, stmp, dt);
        dyn_partial_kernel<<<dgrid, TPB, 0, stream>>>(stmp, part, jchunk);
        finish_final_kernel<S><<<fgrid, 256, 0, stream>>>(part, kb0, kb1, kb2, scur,
                                                          outslot, dt / 6.f);
    }
}

extern "C" void kernel_launch(void* const* d_in, const int* in_sizes, int n_in,
                              void* d_out, int out_size, void* d_ws, size_t ws_size,
                              hipStream_t stream)
{
    const float* mom = (const float*)d_in[0];
    const float* cp  = (const float*)d_in[1];
    float* out = (float*)d_out;
    float* ws  = (float*)d_ws;

    float* scur = ws;
    float* stmp = ws + SSZ;
    float* kb0  = ws + 2 * SSZ;
    float* kb1  = ws + 3 * SSZ;
    float* kb2  = ws + 4 * SSZ;
    float* part = ws + 5 * SSZ;

    const size_t avail_f = ws_size / sizeof(float);
    int S = 128;
    while (S > 4 && (size_t)(5 * SSZ) + (size_t)S * 6 * CN > avail_f) S >>= 1;

    switch (S) {
        case 128: run_steps<128>(mom, cp, out, scur, stmp, kb0, kb1, kb2, part, stream); break;
        case 64:  run_steps<64 >(mom, cp, out, scur, stmp, kb0, kb1, kb2, part, stream); break;
        case 32:  run_steps<32 >(mom, cp, out, scur, stmp, kb0, kb1, kb2, part, stream); break;
        case 16:  run_steps<16 >(mom, cp, out, scur, stmp, kb0, kb1, kb2, part, stream); break;
        default:  run_steps<8  >(mom, cp, out, scur, stmp, kb0, kb1, kb2, part, stream); break;
    }
}

// Round 5
// 671.707 us; speedup vs baseline: 1.4235x; 1.1335x over previous
//
#include <hip/hip_runtime.h>

// Geodesic shooting (Hamiltonian RK4) on MI355X.
// dyn(s) = [K@m, 2 * sum_j (mi.mj) Kij (ci - cj)], K = exp(-||ci-cj||^2), sigma=1.
// j-stream is wave-uniform -> scalar (SGPR) loads from a packed mirror; no LDS.

#define CN   8192
#define TPB  256
#define PTS  2
#define IGRP (TPB * PTS)    // 512 i's per block
#define NIB  (CN / IGRP)    // 16 i-groups
#define SSZ  (2 * CN * 3)   // floats per state

// sqrt(log2(e)): coords pre-scaled so exp(-||.||^2) == exp2(-d2_scaled).
#define CSCALE 1.2011224087864498f
#define FSCALE (2.0f / CSCALE)

// packed mirror: [CN][2] float4 = {c'x,c'y,c'z,0},{mx,my,mz,0}

__global__ __launch_bounds__(TPB, 8) void dyn_partial_kernel(
    const float4* __restrict__ jp, float* __restrict__ part, int jchunk)
{
    const int tid = threadIdx.x;
    const int i0  = blockIdx.x * IGRP + tid;
    const int i1  = i0 + TPB;

    const float4 C0 = jp[2*i0], P0 = jp[2*i0+1];   // ci' (scaled), mi
    const float4 C1 = jp[2*i1], P1 = jp[2*i1+1];

    float g0x=0.f,g0y=0.f,g0z=0.f, f0x=0.f,f0y=0.f,f0z=0.f;
    float g1x=0.f,g1y=0.f,g1z=0.f, f1x=0.f,f1y=0.f,f1z=0.f;

    const int jbeg = blockIdx.y * jchunk;
    const int jend = jbeg + jchunk;
#pragma unroll 4
    for (int j = jbeg; j < jend; ++j) {
        const float4 A = jp[2*j];       // uniform -> s_load (SGPRs)
        const float4 M = jp[2*j+1];
        {
            const float dx = C0.x - A.x, dy = C0.y - A.y, dz = C0.z - A.z;
            const float d2 = fmaf(dx, dx, fmaf(dy, dy, dz*dz));
            const float e  = __builtin_amdgcn_exp2f(-d2);
            const float md = fmaf(P0.x, M.x, fmaf(P0.y, M.y, P0.z * M.z));
            const float w  = md * e;
            g0x = fmaf(e, M.x, g0x); g0y = fmaf(e, M.y, g0y); g0z = fmaf(e, M.z, g0z);
            f0x = fmaf(w, dx, f0x);  f0y = fmaf(w, dy, f0y);  f0z = fmaf(w, dz, f0z);
        }
        {
            const float dx = C1.x - A.x, dy = C1.y - A.y, dz = C1.z - A.z;
            const float d2 = fmaf(dx, dx, fmaf(dy, dy, dz*dz));
            const float e  = __builtin_amdgcn_exp2f(-d2);
            const float md = fmaf(P1.x, M.x, fmaf(P1.y, M.y, P1.z * M.z));
            const float w  = md * e;
            g1x = fmaf(e, M.x, g1x); g1y = fmaf(e, M.y, g1y); g1z = fmaf(e, M.z, g1z);
            f1x = fmaf(w, dx, f1x);  f1y = fmaf(w, dy, f1y);  f1z = fmaf(w, dz, f1z);
        }
    }
    // dm = 2*force_true = FSCALE * f   (dx was in scaled units)
    float* p = part + (size_t)blockIdx.y * (6 * CN);
    p[0*CN+i0] = g0x;        p[1*CN+i0] = g0y;        p[2*CN+i0] = g0z;
    p[3*CN+i0] = FSCALE*f0x; p[4*CN+i0] = FSCALE*f0y; p[5*CN+i0] = FSCALE*f0z;
    p[0*CN+i1] = g1x;        p[1*CN+i1] = g1y;        p[2*CN+i1] = g1z;
    p[3*CN+i1] = FSCALE*f1x; p[4*CN+i1] = FSCALE*f1y; p[5*CN+i1] = FSCALE*f1z;
}

// gidx in [0, 6*CN): plane cd = gidx>>13, i = gidx&8191
__device__ __forceinline__ void decode(int gidx, int& off, int& i, int& comp, int& d) {
    const int cd = gidx >> 13;
    i    = gidx & (CN - 1);
    comp = (cd >= 3) ? 1 : 0;
    d    = cd - comp * 3;
    off  = comp * CN * 3 + i * 3 + d;
}

// Reduce partials over S; store k, stmp = sbase + coef*k, and packed(stmp).
template<int S>
__global__ __launch_bounds__(256) void finish_kernel(
    const float* __restrict__ part, float* __restrict__ kout,
    const float* __restrict__ sbase, float* __restrict__ stmp,
    float* __restrict__ packed, float coef)
{
    constexpr int SQ = S / 4;
    const int tid = threadIdx.x;
    const int sub = tid >> 6, o = tid & 63;
    const int idx = blockIdx.x * 64 + o;
    const float* p = part + (size_t)(sub * SQ) * (6 * CN) + idx;
    float acc = 0.f;
#pragma unroll 8
    for (int r = 0; r < SQ; ++r) acc += p[(size_t)r * (6 * CN)];
    __shared__ float red[256];
    red[tid] = acc;
    __syncthreads();
    if (tid < 64) {
        const float total = red[tid] + red[tid+64] + red[tid+128] + red[tid+192];
        int off, i, comp, d;
        decode(blockIdx.x * 64 + tid, off, i, comp, d);
        kout[off] = total;
        const float v = sbase[off] + coef * total;
        stmp[off] = v;
        packed[i*8 + comp*4 + d] = comp ? v : v * CSCALE;
    }
}

// 4th finish fused with RK4 combine: scur += dt/6*(k1+2k2+2k3+k4); packed(scur); echo out.
template<int S>
__global__ __launch_bounds__(256) void finish_final_kernel(
    const float* __restrict__ part,
    const float* __restrict__ k1, const float* __restrict__ k2, const float* __restrict__ k3,
    float* __restrict__ scur, float* __restrict__ packed,
    float* __restrict__ outslot, float dt6)
{
    constexpr int SQ = S / 4;
    const int tid = threadIdx.x;
    const int sub = tid >> 6, o = tid & 63;
    const int idx = blockIdx.x * 64 + o;
    const float* p = part + (size_t)(sub * SQ) * (6 * CN) + idx;
    float acc = 0.f;
#pragma unroll 8
    for (int r = 0; r < SQ; ++r) acc += p[(size_t)r * (6 * CN)];
    __shared__ float red[256];
    red[tid] = acc;
    __syncthreads();
    if (tid < 64) {
        const float k4 = red[tid] + red[tid+64] + red[tid+128] + red[tid+192];
        int off, i, comp, d;
        decode(blockIdx.x * 64 + tid, off, i, comp, d);
        const float v = scur[off] + dt6 * (k1[off] + 2.f * (k2[off] + k3[off]) + k4);
        scur[off]    = v;
        outslot[off] = v;
        packed[i*8 + comp*4 + d] = comp ? v : v * CSCALE;
    }
}

__global__ __launch_bounds__(256) void init_kernel(
    const float* __restrict__ mom, const float* __restrict__ cp,
    float* __restrict__ out, float* __restrict__ scur, float* __restrict__ packed)
{
    const int idx = blockIdx.x * 256 + threadIdx.x;
    if (idx < 5) out[idx] = 0.25f * (float)idx;      // t_span
    if (idx < CN * 3) {
        const float cv = cp[idx], mv = mom[idx];
        scur[idx]          = cv;
        scur[CN * 3 + idx] = mv;
        out[5 + idx]            = cv;
        out[5 + CN * 3 + idx]   = mv;
        const int i = idx / 3, d = idx - i * 3;
        packed[i*8 + d]     = cv * CSCALE;
        packed[i*8 + 4 + d] = mv;
        if (d == 0) { packed[i*8 + 3] = 0.f; packed[i*8 + 7] = 0.f; }
    }
}

template<int S>
static void run_steps(const float* mom, const float* cp, float* out,
                      float* scur, float* stmp, float* kb0, float* kb1, float* kb2,
                      float* packed, float* part, hipStream_t stream)
{
    const float dt = 0.25f;
    const int jchunk = CN / S;
    const float4* jp = (const float4*)packed;
    init_kernel<<<(CN * 3 + 255) / 256, 256, 0, stream>>>(mom, cp, out, scur, packed);
    dim3 dgrid(NIB, S);
    const int fgrid = 6 * CN / 64;   // 768
    for (int step = 0; step < 4; ++step) {
        float* outslot = out + 5 + (size_t)(step + 1) * SSZ;
        dyn_partial_kernel<<<dgrid, TPB, 0, stream>>>(jp, part, jchunk);
        finish_kernel<S><<<fgrid, 256, 0, stream>>>(part, kb0, scur, stmp, packed, 0.5f * dt);
        dyn_partial_kernel<<<dgrid, TPB, 0, stream>>>(jp, part, jchunk);
        finish_kernel<S><<<fgrid, 256, 0, stream>>>(part, kb1, scur, stmp, packed, 0.5f * dt);
        dyn_partial_kernel<<<dgrid, TPB, 0, stream>>>(jp, part, jchunk);
        finish_kernel<S><<<fgrid, 256, 0, stream>>>(part, kb2, scur, stmp, packed, dt);
        dyn_partial_kernel<<<dgrid, TPB, 0, stream>>>(jp, part, jchunk);
        finish_final_kernel<S><<<fgrid, 256, 0, stream>>>(part, kb0, kb1, kb2, scur, packed,
                                                          outslot, dt / 6.f);
    }
}

extern "C" void kernel_launch(void* const* d_in, const int* in_sizes, int n_in,
                              void* d_out, int out_size, void* d_ws, size_t ws_size,
                              hipStream_t stream)
{
    const float* mom = (const float*)d_in[0];
    const float* cp  = (const float*)d_in[1];
    float* out = (float*)d_out;
    float* ws  = (float*)d_ws;

    float* scur   = ws;
    float* stmp   = ws + SSZ;
    float* kb0    = ws + 2 * SSZ;
    float* kb1    = ws + 3 * SSZ;
    float* kb2    = ws + 4 * SSZ;
    float* packed = ws + 5 * SSZ;          // CN*8
    float* part   = packed + CN * 8;       // S * 6 * CN

    const size_t fixed = 5 * SSZ + CN * 8;
    const size_t avail_f = ws_size / sizeof(float);
    int S = 128;
    while (S > 4 && fixed + (size_t)S * 6 * CN > avail_f) S >>= 1;

    switch (S) {
        case 128: run_steps<128>(mom, cp, out, scur, stmp, kb0, kb1, kb2, packed, part, stream); break;
        case 64:  run_steps<64 >(mom, cp, out, scur, stmp, kb0, kb1, kb2, packed, part, stream); break;
        case 32:  run_steps<32 >(mom, cp, out, scur, stmp, kb0, kb1, kb2, packed, part, stream); break;
        case 16:  run_steps<16 >(mom, cp, out, scur, stmp, kb0, kb1, kb2, packed, part, stream); break;
        default:  run_steps<8  >(mom, cp, out, scur, stmp, kb0, kb1, kb2, packed, part, stream); break;
    }
}